// Round 13
// baseline (399.970 us; speedup 1.0000x reference)
//
#include <hip/hip_runtime.h>
#include <math.h>

// ---- problem constants ----
#define N_NODES 33
#define SEQ 24
#define BATCH 64
#define G_GRAPHS (BATCH * SEQ)          // 1536
#define EPG 64
#define E_EDGES (G_GRAPHS * EPG)        // 98304
#define N_TOTAL (G_GRAPHS * N_NODES)    // 50688
#define HID 64
#define HEADS 8
#define HC (HID * HEADS)                // 512
#define LSTM1_H 128
#define LSTM2_H 64
#define NEG_SLOPE 0.2f

__device__ __forceinline__ float sigmoidf_(float x) { return 1.f / (1.f + expf(-x)); }
__device__ __forceinline__ float eluf_(float x) { return x > 0.f ? x : expm1f(x); }
__device__ __forceinline__ float lreluf_(float x) { return x > 0.f ? x : NEG_SLOPE * x; }

typedef __attribute__((ext_vector_type(4))) float f32x4;
typedef _Float16 half_t;
typedef __attribute__((ext_vector_type(8))) _Float16 halfx8;

__device__ __forceinline__ void gl2lds16(const void* g, void* l) {
  __builtin_amdgcn_global_load_lds(
      (__attribute__((address_space(1))) const unsigned int*)g,
      (__attribute__((address_space(3))) unsigned int*)l, 16, 0, 0);
}

// ============================================================
// GAT layer 1 (round-4 task maps, verified) -> h1 single fp16.
// ============================================================
__global__ __launch_bounds__(256) void gat1_kernel(
    const float* __restrict__ x, const int* __restrict__ src, const int* __restrict__ dst,
    const float* __restrict__ ea, const float* __restrict__ Wl, const float* __restrict__ Wr,
    const float* __restrict__ We, const float* __restrict__ att, const float* __restrict__ bias,
    half_t* __restrict__ h1, int g0) {
  __shared__ alignas(16) float Wl_s[2 * 512];
  __shared__ alignas(16) float Wr_s[2 * 512];
  __shared__ alignas(16) float We_s[3 * 512];
  __shared__ alignas(16) float att_s[512];
  __shared__ float xs0_s[N_NODES + 1], xs1_s[N_NODES + 1];
  __shared__ float easX[EPG], easY[EPG], easZ[EPG];
  __shared__ float logit_s[HEADS * 65];   // padded stride 65
  __shared__ int sloc[EPG], dloc[EPG], deg[N_NODES], start[N_NODES], fill[N_NODES], elist[EPG];

  const int g = g0 + blockIdx.x, tid = threadIdx.x;
  const int nb = g * N_NODES, eb = g * EPG;
  const int lb = blockIdx.x * N_NODES;

  for (int i = tid; i < 1024; i += 256) { Wl_s[i] = Wl[i]; Wr_s[i] = Wr[i]; }
  for (int i = tid; i < 1536; i += 256) We_s[i] = We[i];
  for (int i = tid; i < 512; i += 256) att_s[i] = att[i];
  if (tid < 2 * N_NODES) {
    float v = x[nb * 2 + tid];
    if (tid & 1) xs1_s[tid >> 1] = v; else xs0_s[tid >> 1] = v;
  }
  if (tid < EPG) {
    easX[tid] = ea[(eb + tid) * 3 + 0];
    easY[tid] = ea[(eb + tid) * 3 + 1];
    easZ[tid] = ea[(eb + tid) * 3 + 2];
    sloc[tid] = src[eb + tid] - nb;
    dloc[tid] = dst[eb + tid] - nb;
  }
  if (tid < N_NODES) { deg[tid] = 0; fill[tid] = 0; }
  __syncthreads();
  if (tid < EPG) atomicAdd(&deg[dloc[tid]], 1);
  __syncthreads();
  if (tid == 0) { int a = 0; for (int n = 0; n < N_NODES; ++n) { start[n] = a; a += deg[n]; } }
  __syncthreads();
  if (tid < EPG) { int d = dloc[tid]; int p = atomicAdd(&fill[d], 1); elist[start[d] + p] = tid; }

  // logits: h = t>>6 (wave-uniform), e = t&63 (= lane). Weight reads broadcast.
  for (int t = tid; t < EPG * HEADS; t += 256) {
    int h = t >> 6, e = t & 63;
    int s = sloc[e], d = dloc[e];
    float xs0 = xs0_s[s], xs1 = xs1_s[s], xd0 = xs0_s[d], xd1 = xs1_s[d];
    float e0 = easX[e], e1 = easY[e], e2 = easZ[e];
    float acc = 0.f;
    int base = h * 64;
    #pragma unroll
    for (int c4 = 0; c4 < 16; ++c4) {
      int j = base + c4 * 4;
      f32x4 wl0 = *(const f32x4*)(Wl_s + j);
      f32x4 wl1 = *(const f32x4*)(Wl_s + 512 + j);
      f32x4 wr0 = *(const f32x4*)(Wr_s + j);
      f32x4 wr1 = *(const f32x4*)(Wr_s + 512 + j);
      f32x4 we0 = *(const f32x4*)(We_s + j);
      f32x4 we1 = *(const f32x4*)(We_s + 512 + j);
      f32x4 we2 = *(const f32x4*)(We_s + 1024 + j);
      f32x4 at  = *(const f32x4*)(att_s + j);
      #pragma unroll
      for (int q = 0; q < 4; ++q) {
        float v = xs0 * wl0[q] + xs1 * wl1[q]
                + xd0 * wr0[q] + xd1 * wr1[q]
                + e0 * we0[q] + e1 * we1[q] + e2 * we2[q];
        acc += lreluf_(v) * at[q];
      }
    }
    logit_s[h * 65 + e] = acc;
  }
  __syncthreads();

  // segment softmax: h = t>>6 (uniform), n = t&63 (lane), skip n>=33
  for (int t = tid; t < HEADS * 64; t += 256) {
    int h = t >> 6, n = t & 63;
    if (n < N_NODES) {
      int s0 = start[n], dn = deg[n];
      float mx = -1e30f;
      for (int i = 0; i < dn; ++i) mx = fmaxf(mx, logit_s[h * 65 + elist[s0 + i]]);
      float den = 0.f;
      for (int i = 0; i < dn; ++i) den += expf(logit_s[h * 65 + elist[s0 + i]] - mx);
      float inv = 1.f / (den + 1e-16f);
      for (int i = 0; i < dn; ++i) {
        int e = elist[s0 + i];
        logit_s[h * 65 + e] = expf(logit_s[h * 65 + e] - mx) * inv;
      }
    }
  }
  __syncthreads();

  // aggregation: task = (n, 8-channel block). n = t>>6 wave-uniform, jb = lane.
  for (int t = tid; t < N_NODES * 64; t += 256) {
    int n = t >> 6, jb = t & 63;
    int j0 = jb * 8, h = jb >> 3;
    f32x4 wa0 = *(const f32x4*)(Wl_s + j0);
    f32x4 wa1 = *(const f32x4*)(Wl_s + j0 + 4);
    f32x4 wb0 = *(const f32x4*)(Wl_s + 512 + j0);
    f32x4 wb1 = *(const f32x4*)(Wl_s + 512 + j0 + 4);
    float acc[8] = {};
    int s0 = start[n], dn = deg[n];
    for (int i = 0; i < dn; ++i) {
      int e = elist[s0 + i]; int s = sloc[e];
      float a = logit_s[h * 65 + e];
      float ax0 = a * xs0_s[s], ax1 = a * xs1_s[s];
      #pragma unroll
      for (int q = 0; q < 4; ++q) {
        acc[q]     += ax0 * wa0[q] + ax1 * wb0[q];
        acc[4 + q] += ax0 * wa1[q] + ax1 * wb1[q];
      }
    }
    f32x4 b0 = *(const f32x4*)(bias + j0);
    f32x4 b1 = *(const f32x4*)(bias + j0 + 4);
    halfx8 vh;
    #pragma unroll
    for (int cc = 0; cc < 8; ++cc) {
      float bb = (cc < 4) ? b0[cc] : b1[cc - 4];
      vh[cc] = (half_t)eluf_(acc[cc] + bb);
    }
    *(halfx8*)(h1 + (size_t)(lb + n) * HC + j0) = vh;
  }
}

// ============================================================
// merged weight conversion to fp16 (unchanged)
// ============================================================
__global__ __launch_bounds__(256) void conv_all(
    const float* __restrict__ Wl, const float* __restrict__ Wr,
    half_t* __restrict__ B2, const float* __restrict__ W1, half_t* __restrict__ W1f) {
  int b = blockIdx.x;
  if (b < 2048) {
    int idx = b * 256 + threadIdx.x;   // n*512 + k
    int n = idx >> 9, k = idx & 511;
    float v = (n < 512) ? Wl[k * 512 + n] : Wr[k * 512 + (n - 512)];
    B2[idx] = (half_t)v;
  } else {
    int idx = (b - 2048) * 256 + threadIdx.x;
    if (idx < 512 * 2112) W1f[idx] = (half_t)W1[idx];
  }
}

// ============================================================
// single-term fp16 MFMA GEMM, round-13 issue-efficiency version:
//  - K/SA/SB compile-time -> staging addresses strength-reduce (round-12
//    VALUBusy 44.6% was the top pipe)
//  - XOR-swizzled LDS staging: 16B unit u of row r lives at slot
//    u ^ s(r), s(r) = (r&3)^((r>>2)&3) over the 16-row window. Fetch lane
//    permutation matches. Fragment reads then alias at most 2-way (free,
//    m136) vs 8-way before (6.5e6 conflict cycles measured round-12).
//  - fp16 epilogue via LDS bounce (reuses staging LDS as [128][132] tile):
//    8 dwordx4 stores/thread instead of 64 scalar 2B stores.
// XCD-aware 1D grid swizzle (round-8 verified).
// ROUND-6 LESSON: never stream an MFMA operand global->VGPR.
// ============================================================
template <int WM, int WN, int NP, int K, int SA, int SB, typename TC>
__global__ __launch_bounds__(256) void gemm_f16(
    const half_t* __restrict__ A, const half_t* __restrict__ B,
    TC* __restrict__ C, const float* __restrict__ bias1, const float* __restrict__ bias2,
    int M, int N) {
  constexpr int BM = 32 * WM, BN = 32 * WN;
  constexpr bool BOUNCE = (sizeof(TC) == 2) && (BM == 128) && (BN == 128);
  constexpr int STAGE_HALFS = (BM + BN) * 32 * NP;
  constexpr int CT_HALFS = BOUNCE ? 128 * 132 : 0;
  constexpr int LDS_HALFS = STAGE_HALFS > CT_HALFS ? STAGE_HALFS : CT_HALFS;
  __shared__ half_t lds[LDS_HALFS];
  half_t* A_s = lds;                        // [NP][BM][32] (swizzled units)
  half_t* B_s = A_s + NP * BM * 32;         // [NP][BN][32]

  const int R = M / BM, NT = N / BN;
  int b = blockIdx.x;
  int xcd = b & 7, q = b >> 3;
  int ct = q % NT, rg = q / NT;
  int r = rg * 8 + xcd;
  if (r >= R) return;

  const int tid = threadIdx.x;
  const int wave = tid >> 6, lane = tid & 63;
  const int wm = wave >> 1, wn = wave & 1;
  const int bm = r * BM, bn = ct * BN;

  const int rA = lane >> 2;                       // local row in 16-row window
  const int swz = (rA & 3) ^ ((rA >> 2) & 3);     // swizzle key for this row
  const int cA = ((lane & 3) ^ swz) * 8;          // permuted global 16B unit

  f32x4 acc[WM][WN];
  #pragma unroll
  for (int tm = 0; tm < WM; ++tm)
    #pragma unroll
    for (int tn = 0; tn < WN; ++tn) acc[tm][tn] = {0.f, 0.f, 0.f, 0.f};

  for (int k0 = 0; k0 < K; k0 += 32 * NP) {
    #pragma unroll
    for (int p = 0; p < NP; ++p) {
      int kk = k0 + p * 32;
      #pragma unroll
      for (int i = 0; i < BM / 64; ++i) {
        int row = i * 64 + wave * 16;
        gl2lds16(A + (size_t)(bm + row + rA) * SA + kk + cA,
                 A_s + p * BM * 32 + row * 32);
      }
      #pragma unroll
      for (int i = 0; i < BN / 64; ++i) {
        int row = i * 64 + wave * 16;
        gl2lds16(B + (size_t)(bn + row + rA) * SB + kk + cA,
                 B_s + p * BN * 32 + row * 32);
      }
    }
    __syncthreads();

    const int fr = lane & 15;
    const int fs = (fr & 3) ^ ((fr >> 2) & 3);      // same key at read time
    const int fk = ((lane >> 4) ^ fs) * 8;          // de-swizzled unit slot
    #pragma unroll
    for (int p = 0; p < NP; ++p) {
      const int pA = p * BM * 32, pB = p * BN * 32;
      halfx8 af[WM], bf[WN];
      #pragma unroll
      for (int tm = 0; tm < WM; ++tm) {
        int rr = (wm * WM + tm) * 16 + fr;
        af[tm] = *(const halfx8*)(A_s + pA + rr * 32 + fk);
      }
      #pragma unroll
      for (int tn = 0; tn < WN; ++tn) {
        int rr = (wn * WN + tn) * 16 + fr;
        bf[tn] = *(const halfx8*)(B_s + pB + rr * 32 + fk);
      }
      #pragma unroll
      for (int tm = 0; tm < WM; ++tm)
        #pragma unroll
        for (int tn = 0; tn < WN; ++tn)
          acc[tm][tn] = __builtin_amdgcn_mfma_f32_16x16x32_f16(af[tm], bf[tn], acc[tm][tn], 0, 0, 0);
    }
    __syncthreads();
  }

  // epilogue: C/D layout col=lane&15, row=(lane>>4)*4+reg  [m89/m91 verified]
  const int col0 = lane & 15, rq = (lane >> 4) * 4;
  if constexpr (BOUNCE) {
    // stage fp16 tile in LDS (row stride 132 halfs: quad groups land on
    // disjoint bank octets), then 16B coalesced stores.
    half_t* Cs = lds;
    #pragma unroll
    for (int tm = 0; tm < WM; ++tm)
      #pragma unroll
      for (int tn = 0; tn < WN; ++tn) {
        int cl = (wn * WN + tn) * 16 + col0;
        #pragma unroll
        for (int rr = 0; rr < 4; ++rr) {
          int rl = (wm * WM + tm) * 16 + rq + rr;
          Cs[rl * 132 + cl] = (half_t)acc[tm][tn][rr];
        }
      }
    __syncthreads();
    #pragma unroll
    for (int pass = 0; pass < 8; ++pass) {
      int row = pass * 16 + (tid >> 4);
      int col = (tid & 15) * 8;
      halfx8 v = *(const halfx8*)(Cs + row * 132 + col);
      *(halfx8*)((half_t*)C + (size_t)(bm + row) * N + bn + col) = v;
    }
  } else {
    #pragma unroll
    for (int tm = 0; tm < WM; ++tm)
      #pragma unroll
      for (int tn = 0; tn < WN; ++tn) {
        int col = bn + (wn * WN + tn) * 16 + col0;
        float badd = 0.f;
        if (bias1) badd += bias1[col];
        if (bias2) badd += bias2[col];
        #pragma unroll
        for (int rr = 0; rr < 4; ++rr) {
          int row = bm + (wm * WM + tm) * 16 + rq + rr;
          C[(size_t)row * N + col] = (TC)(acc[tm][tn][rr] + badd);
        }
      }
  }
}

// ============================================================
// GAT layer 2 v4 (round-11/12 verified) -> h2 single fp16.
// ============================================================
__global__ __launch_bounds__(256) void gat2_kernel(
    const half_t* __restrict__ xlr, const int* __restrict__ src, const int* __restrict__ dst,
    const float* __restrict__ ea, const float* __restrict__ We,
    const float* __restrict__ att, const float* __restrict__ bias,
    half_t* __restrict__ h2, int g0) {
  __shared__ alignas(16) float We_s[3 * 512];
  __shared__ alignas(16) float att_s[512];
  __shared__ float b_s[HID];
  __shared__ float easX[EPG], easY[EPG], easZ[EPG];
  __shared__ float logit_s[HEADS * 65];
  __shared__ int sloc[EPG], dloc[EPG], deg[N_NODES], start[N_NODES], fill[N_NODES], elist[EPG];

  const int g = g0 + blockIdx.x, tid = threadIdx.x;
  const int nb = g * N_NODES, eb = g * EPG;
  const int lb = blockIdx.x * N_NODES;
  const int wave = tid >> 6, lane = tid & 63;

  for (int i = tid; i < 1536; i += 256) We_s[i] = We[i];
  for (int i = tid; i < 512; i += 256) att_s[i] = att[i];
  if (tid < HID) b_s[tid] = bias[tid];
  if (tid < EPG) {
    easX[tid] = ea[(eb + tid) * 3 + 0];
    easY[tid] = ea[(eb + tid) * 3 + 1];
    easZ[tid] = ea[(eb + tid) * 3 + 2];
    sloc[tid] = src[eb + tid] - nb;
    dloc[tid] = dst[eb + tid] - nb;
  }
  if (tid < N_NODES) { deg[tid] = 0; fill[tid] = 0; }
  __syncthreads();
  if (tid < EPG) atomicAdd(&deg[dloc[tid]], 1);
  __syncthreads();
  if (tid == 0) { int a = 0; for (int n = 0; n < N_NODES; ++n) { start[n] = a; a += deg[n]; } }
  __syncthreads();
  if (tid < EPG) { int d = dloc[tid]; int p = atomicAdd(&fill[d], 1); elist[start[d] + p] = tid; }
  __syncthreads();

  // hoist per-lane weights into registers (channels j0 = lane*8 .. +7)
  const int j0 = lane * 8;
  float w0[8], w1[8], w2[8], at8[8];
  #pragma unroll
  for (int q = 0; q < 8; ++q) {
    w0[q] = We_s[j0 + q];
    w1[q] = We_s[512 + j0 + q];
    w2[q] = We_s[1024 + j0 + q];
    at8[q] = att_s[j0 + q];
  }

  // logits: one wave per edge; lane -> 8 channels; head = lane>>3
  for (int e = wave; e < EPG; e += 4) {
    int s = sloc[e], d = dloc[e];          // wave-uniform LDS broadcast
    halfx8 xlv = *((const halfx8*)(xlr + (size_t)(lb + s) * 1024) + lane);
    halfx8 xrv = *((const halfx8*)(xlr + (size_t)(lb + d) * 1024 + 512) + lane);
    float e0 = easX[e], e1 = easY[e], e2 = easZ[e];
    float acc = 0.f;
    #pragma unroll
    for (int q = 0; q < 8; ++q) {
      float v = (float)xlv[q] + (float)xrv[q] + e0 * w0[q] + e1 * w1[q] + e2 * w2[q];
      acc += lreluf_(v) * at8[q];
    }
    acc += __shfl_xor(acc, 1, 64);
    acc += __shfl_xor(acc, 2, 64);
    acc += __shfl_xor(acc, 4, 64);
    if ((lane & 7) == 0) logit_s[(lane >> 3) * 65 + e] = acc;
  }
  __syncthreads();

  // softmax: h = t>>6 (uniform), n = t&63 (lane), skip n>=33
  for (int t = tid; t < HEADS * 64; t += 256) {
    int h = t >> 6, n = t & 63;
    if (n < N_NODES) {
      int s0 = start[n], dn = deg[n];
      float mx = -1e30f;
      for (int i = 0; i < dn; ++i) mx = fmaxf(mx, logit_s[h * 65 + elist[s0 + i]]);
      float den = 0.f;
      for (int i = 0; i < dn; ++i) den += expf(logit_s[h * 65 + elist[s0 + i]] - mx);
      float inv = 1.f / (den + 1e-16f);
      for (int i = 0; i < dn; ++i) {
        int e = elist[s0 + i];
        logit_s[h * 65 + e] = expf(logit_s[h * 65 + e] - mx) * inv;
      }
    }
  }
  __syncthreads();

  // aggregation: wave-task n, lane = HID channel; head-mean fused (x0.125)
  for (int n = wave; n < N_NODES; n += 4) {
    float acc = 0.f;
    int s0 = start[n], dn = deg[n];
    for (int i = 0; i < dn; ++i) {
      int e = elist[s0 + i], s = sloc[e];
      const half_t* row = xlr + (size_t)(lb + s) * 1024 + lane;
      #pragma unroll
      for (int h = 0; h < 8; ++h)
        acc += logit_s[h * 65 + e] * (float)row[h * 64];
    }
    float v = eluf_(acc * 0.125f + b_s[lane]);
    h2[(size_t)(nb + n) * HID + lane] = (half_t)v;
  }
}

// ============================================================
// LSTM1 (round-5 no-spill version) + rest of the chain
// ============================================================
__global__ __launch_bounds__(1024, 4) void lstm1_kernel(
    const float* __restrict__ X, const float* __restrict__ Whh, float* __restrict__ Y) {
  __shared__ float hs[LSTM1_H], cs[LSTM1_H], part[4 * LSTM1_H], gs[4 * LSTM1_H];
  const int tid = threadIdx.x;
  const int j = tid & 511, half = tid >> 9;
  const int b = blockIdx.x;
  float4 w[16];
  const float4* wp = (const float4*)(Whh + (size_t)j * LSTM1_H + half * 64);
  #pragma unroll
  for (int q = 0; q < 16; ++q) w[q] = wp[q];
  if (tid < LSTM1_H) { hs[tid] = 0.f; cs[tid] = 0.f; }
  __syncthreads();
  for (int t = 0; t < SEQ; ++t) {
    const float* hb = hs + half * 64;
    float acc = 0.f;
    #pragma unroll
    for (int q = 0; q < 16; ++q) {
      acc += w[q].x * hb[4 * q] + w[q].y * hb[4 * q + 1]
           + w[q].z * hb[4 * q + 2] + w[q].w * hb[4 * q + 3];
    }
    if (half) part[j] = acc;
    __syncthreads();
    if (!half) gs[j] = acc + part[j] + X[((size_t)b * SEQ + t) * 512 + j];
    __syncthreads();
    if (tid < LSTM1_H) {
      float ig = sigmoidf_(gs[tid]);
      float fg = sigmoidf_(gs[LSTM1_H + tid]);
      float gg = tanhf(gs[2 * LSTM1_H + tid]);
      float og = sigmoidf_(gs[3 * LSTM1_H + tid]);
      float c = fg * cs[tid] + ig * gg;
      cs[tid] = c;
      float h = og * tanhf(c);
      hs[tid] = h;
      Y[((size_t)b * SEQ + t) * LSTM1_H + tid] = h;
    }
    __syncthreads();
  }
}

__global__ __launch_bounds__(256) void x2_kernel(
    const float* __restrict__ Y1, const float* __restrict__ Wih,
    const float* __restrict__ bih, const float* __restrict__ bhh,
    float* __restrict__ X2) {
  __shared__ float ys[LSTM1_H];
  const int g = blockIdx.x, j = threadIdx.x;
  if (j < LSTM1_H) ys[j] = Y1[(size_t)g * LSTM1_H + j];
  __syncthreads();
  const float4* wp = (const float4*)(Wih + (size_t)j * LSTM1_H);
  float acc = bih[j] + bhh[j];
  #pragma unroll
  for (int q = 0; q < 32; ++q) {
    float4 w = wp[q];
    acc += w.x * ys[4 * q] + w.y * ys[4 * q + 1] + w.z * ys[4 * q + 2] + w.w * ys[4 * q + 3];
  }
  X2[(size_t)g * 256 + j] = acc;
}

__global__ __launch_bounds__(256, 2) void lstm2_fc_kernel(
    const float* __restrict__ X, const float* __restrict__ Whh,
    const float* __restrict__ fcW, const float* __restrict__ fcb,
    float* __restrict__ out) {
  __shared__ float hs[LSTM2_H], cs[LSTM2_H], gs[4 * LSTM2_H];
  const int b = blockIdx.x, j = threadIdx.x;
  float4 w[16];
  const float4* wp = (const float4*)(Whh + (size_t)j * LSTM2_H);
  #pragma unroll
  for (int q = 0; q < 16; ++q) w[q] = wp[q];
  if (j < LSTM2_H) { hs[j] = 0.f; cs[j] = 0.f; }
  __syncthreads();
  for (int t = 0; t < SEQ; ++t) {
    float acc = X[((size_t)b * SEQ + t) * 256 + j];
    #pragma unroll
    for (int q = 0; q < 16; ++q) {
      acc += w[q].x * hs[4 * q] + w[q].y * hs[4 * q + 1]
           + w[q].z * hs[4 * q + 2] + w[q].w * hs[4 * q + 3];
    }
    gs[j] = acc;
    __syncthreads();
    if (j < LSTM2_H) {
      float ig = sigmoidf_(gs[j]);
      float fg = sigmoidf_(gs[LSTM2_H + j]);
      float gg = tanhf(gs[2 * LSTM2_H + j]);
      float og = sigmoidf_(gs[3 * LSTM2_H + j]);
      float c = fg * cs[j] + ig * gg;
      cs[j] = c;
      hs[j] = og * tanhf(c);
    }
    __syncthreads();
  }
  if (j < 4) {
    float acc = fcb[j];
    #pragma unroll
    for (int k = 0; k < LSTM2_H; ++k) acc += fcW[j * LSTM2_H + k] * hs[k];
    out[b * 4 + j] = acc;
  }
}

// ============================================================
extern "C" void kernel_launch(void* const* d_in, const int* in_sizes, int n_in,
                              void* d_out, int out_size, void* d_ws, size_t ws_size,
                              hipStream_t stream) {
  const float* x       = (const float*)d_in[0];
  const int*   eidx    = (const int*)d_in[1];
  const float* eattr   = (const float*)d_in[2];
  const float* g1_Wl   = (const float*)d_in[3];
  const float* g1_Wr   = (const float*)d_in[4];
  const float* g1_We   = (const float*)d_in[5];
  const float* g1_att  = (const float*)d_in[6];
  const float* g1_b    = (const float*)d_in[7];
  const float* g2_Wl   = (const float*)d_in[8];
  const float* g2_Wr   = (const float*)d_in[9];
  const float* g2_We   = (const float*)d_in[10];
  const float* g2_att  = (const float*)d_in[11];
  const float* g2_b    = (const float*)d_in[12];
  const float* l1_Wih  = (const float*)d_in[13];
  const float* l1_Whh  = (const float*)d_in[14];
  const float* l1_bih  = (const float*)d_in[15];
  const float* l1_bhh  = (const float*)d_in[16];
  const float* l2_Wih  = (const float*)d_in[17];
  const float* l2_Whh  = (const float*)d_in[18];
  const float* l2_bih  = (const float*)d_in[19];
  const float* l2_bhh  = (const float*)d_in[20];
  const float* fc_W    = (const float*)d_in[21];
  const float* fc_b    = (const float*)d_in[22];
  float* out = (float*)d_out;

  const int* src = eidx;
  const int* dst = eidx + E_EDGES;

  // ---- runtime-adaptive chunking: largest chunk size whose ws layout fits.
  const int cand[5] = {1, 2, 3, 4, 6};
  int nchunks = 0;
  half_t *h1 = nullptr, *xlr2c = nullptr, *h2 = nullptr, *B2 = nullptr, *W1f = nullptr;
  float *X1 = nullptr, *Y1 = nullptr, *X2 = nullptr;
  int chunk_g = 0, chunk_n = 0;
  for (int ci = 0; ci < 5; ++ci) {
    int C = cand[ci];
    int CG = G_GRAPHS / C, CN = CG * N_NODES;
    char* p = (char*)d_ws;
    auto alloc = [&](size_t bytes) { char* r = p; p += (bytes + 255) & ~(size_t)255; return r; };
    half_t* t_h1    = (half_t*)alloc((size_t)CN * HC * 2);
    half_t* t_xlr2c = (half_t*)alloc((size_t)CN * 1024 * 2);
    half_t* t_h2    = (half_t*)alloc((size_t)G_GRAPHS * 2112 * 2);
    half_t* t_B2    = (half_t*)alloc((size_t)1024 * 512 * 2);
    half_t* t_W1f   = (half_t*)alloc((size_t)512 * 2112 * 2);
    float*  t_X1    = (float*)alloc((size_t)G_GRAPHS * 512 * 4);
    float*  t_Y1    = (float*)alloc((size_t)G_GRAPHS * LSTM1_H * 4);
    float*  t_X2    = (float*)alloc((size_t)G_GRAPHS * 256 * 4);
    if ((size_t)(p - (char*)d_ws) <= ws_size) {
      nchunks = C; chunk_g = CG; chunk_n = CN;
      h1 = t_h1; xlr2c = t_xlr2c; h2 = t_h2; B2 = t_B2; W1f = t_W1f;
      X1 = t_X1; Y1 = t_Y1; X2 = t_X2;
      break;
    }
  }
  if (nchunks == 0) return;   // guard: zero output instead of memory fault

  conv_all<<<2048 + (512 * 2112 + 255) / 256, 256, 0, stream>>>(
      g2_Wl, g2_Wr, B2, l1_Wih, W1f);

  for (int c = 0; c < nchunks; ++c) {
    int g0 = c * chunk_g;
    gat1_kernel<<<chunk_g, 256, 0, stream>>>(x, src, dst, eattr, g1_Wl, g1_Wr, g1_We,
                                             g1_att, g1_b, h1, g0);
    // 128x128 tiles, BK=64, fp16 1-term, XCD-swizzled 1D grid
    int R = chunk_n / 128, NT = 1024 / 128;
    int gblocks = 8 * ((R + 7) / 8) * NT;
    gemm_f16<4, 4, 2, HC, HC, HC, half_t><<<gblocks, 256, 0, stream>>>(
        h1, B2, xlr2c, (const float*)nullptr, (const float*)nullptr,
        chunk_n, 1024);
    gat2_kernel<<<chunk_g, 256, 0, stream>>>(xlr2c, src, dst, eattr, g2_We,
                                             g2_att, g2_b, h2, g0);
  }

  // X1 = h2 @ l1_Wih^T + biases  (single dispatch, 64x64 tiles, BK=64)
  {
    int R = G_GRAPHS / 64, NT = 512 / 64;
    int gblocks = 8 * ((R + 7) / 8) * NT;
    gemm_f16<2, 2, 2, N_NODES * HID, N_NODES * HID, N_NODES * HID, float>
        <<<gblocks, 256, 0, stream>>>(
        h2, W1f, X1, l1_bih, l1_bhh, G_GRAPHS, 512);
  }

  lstm1_kernel<<<BATCH, 1024, 0, stream>>>(X1, l1_Whh, Y1);
  x2_kernel<<<G_GRAPHS, 256, 0, stream>>>(Y1, l2_Wih, l2_bih, l2_bhh, X2);
  lstm2_fc_kernel<<<BATCH, 256, 0, stream>>>(X2, l2_Whh, fc_W, fc_b, out);
}

// Round 14
// 355.759 us; speedup vs baseline: 1.1243x; 1.1243x over previous
//
#include <hip/hip_runtime.h>
#include <math.h>

// ---- problem constants ----
#define N_NODES 33
#define SEQ 24
#define BATCH 64
#define G_GRAPHS (BATCH * SEQ)          // 1536
#define EPG 64
#define E_EDGES (G_GRAPHS * EPG)        // 98304
#define N_TOTAL (G_GRAPHS * N_NODES)    // 50688
#define HID 64
#define HEADS 8
#define HC (HID * HEADS)                // 512
#define LSTM1_H 128
#define LSTM2_H 64
#define NEG_SLOPE 0.2f
#define CONV_BLOCKS (2048 + (512 * 2112 + 255) / 256)   // 6272

__device__ __forceinline__ float sigmoidf_(float x) { return 1.f / (1.f + expf(-x)); }
__device__ __forceinline__ float eluf_(float x) { return x > 0.f ? x : expm1f(x); }
__device__ __forceinline__ float lreluf_(float x) { return x > 0.f ? x : NEG_SLOPE * x; }

typedef __attribute__((ext_vector_type(4))) float f32x4;
typedef _Float16 half_t;
typedef __attribute__((ext_vector_type(8))) _Float16 halfx8;

__device__ __forceinline__ void gl2lds16(const void* g, void* l) {
  __builtin_amdgcn_global_load_lds(
      (__attribute__((address_space(1))) const unsigned int*)g,
      (__attribute__((address_space(3))) unsigned int*)l, 16, 0, 0);
}

// ============================================================
// GAT layer 1 (round-4 task maps, verified) -> h1 single fp16.
// Blocks >= gat_blocks do the one-time fp16 weight conversion instead
// (fused former conv_all; block-uniform branch, no shared barriers crossed).
// ============================================================
__global__ __launch_bounds__(256) void gat1_kernel(
    const float* __restrict__ x, const int* __restrict__ src, const int* __restrict__ dst,
    const float* __restrict__ ea, const float* __restrict__ Wl, const float* __restrict__ Wr,
    const float* __restrict__ We, const float* __restrict__ att, const float* __restrict__ bias,
    half_t* __restrict__ h1, int g0, int gat_blocks,
    const float* __restrict__ g2Wl, const float* __restrict__ g2Wr,
    half_t* __restrict__ B2, const float* __restrict__ W1, half_t* __restrict__ W1f) {
  const int tid = threadIdx.x;
  if ((int)blockIdx.x >= gat_blocks) {
    int cb = blockIdx.x - gat_blocks;
    if (cb < 2048) {
      int idx = cb * 256 + tid;   // n*512 + k
      int n = idx >> 9, k = idx & 511;
      float v = (n < 512) ? g2Wl[k * 512 + n] : g2Wr[k * 512 + (n - 512)];
      B2[idx] = (half_t)v;
    } else {
      int idx = (cb - 2048) * 256 + tid;
      if (idx < 512 * 2112) W1f[idx] = (half_t)W1[idx];
    }
    return;
  }

  __shared__ alignas(16) float Wl_s[2 * 512];
  __shared__ alignas(16) float Wr_s[2 * 512];
  __shared__ alignas(16) float We_s[3 * 512];
  __shared__ alignas(16) float att_s[512];
  __shared__ float xs0_s[N_NODES + 1], xs1_s[N_NODES + 1];
  __shared__ float easX[EPG], easY[EPG], easZ[EPG];
  __shared__ float logit_s[HEADS * 65];   // padded stride 65
  __shared__ int sloc[EPG], dloc[EPG], deg[N_NODES], start[N_NODES], fill[N_NODES], elist[EPG];

  const int g = g0 + blockIdx.x;
  const int nb = g * N_NODES, eb = g * EPG;
  const int lb = blockIdx.x * N_NODES;

  for (int i = tid; i < 1024; i += 256) { Wl_s[i] = Wl[i]; Wr_s[i] = Wr[i]; }
  for (int i = tid; i < 1536; i += 256) We_s[i] = We[i];
  for (int i = tid; i < 512; i += 256) att_s[i] = att[i];
  if (tid < 2 * N_NODES) {
    float v = x[nb * 2 + tid];
    if (tid & 1) xs1_s[tid >> 1] = v; else xs0_s[tid >> 1] = v;
  }
  if (tid < EPG) {
    easX[tid] = ea[(eb + tid) * 3 + 0];
    easY[tid] = ea[(eb + tid) * 3 + 1];
    easZ[tid] = ea[(eb + tid) * 3 + 2];
    sloc[tid] = src[eb + tid] - nb;
    dloc[tid] = dst[eb + tid] - nb;
  }
  if (tid < N_NODES) { deg[tid] = 0; fill[tid] = 0; }
  __syncthreads();
  if (tid < EPG) atomicAdd(&deg[dloc[tid]], 1);
  __syncthreads();
  if (tid == 0) { int a = 0; for (int n = 0; n < N_NODES; ++n) { start[n] = a; a += deg[n]; } }
  __syncthreads();
  if (tid < EPG) { int d = dloc[tid]; int p = atomicAdd(&fill[d], 1); elist[start[d] + p] = tid; }

  for (int t = tid; t < EPG * HEADS; t += 256) {
    int h = t >> 6, e = t & 63;
    int s = sloc[e], d = dloc[e];
    float xs0 = xs0_s[s], xs1 = xs1_s[s], xd0 = xs0_s[d], xd1 = xs1_s[d];
    float e0 = easX[e], e1 = easY[e], e2 = easZ[e];
    float acc = 0.f;
    int base = h * 64;
    #pragma unroll
    for (int c4 = 0; c4 < 16; ++c4) {
      int j = base + c4 * 4;
      f32x4 wl0 = *(const f32x4*)(Wl_s + j);
      f32x4 wl1 = *(const f32x4*)(Wl_s + 512 + j);
      f32x4 wr0 = *(const f32x4*)(Wr_s + j);
      f32x4 wr1 = *(const f32x4*)(Wr_s + 512 + j);
      f32x4 we0 = *(const f32x4*)(We_s + j);
      f32x4 we1 = *(const f32x4*)(We_s + 512 + j);
      f32x4 we2 = *(const f32x4*)(We_s + 1024 + j);
      f32x4 at  = *(const f32x4*)(att_s + j);
      #pragma unroll
      for (int q = 0; q < 4; ++q) {
        float v = xs0 * wl0[q] + xs1 * wl1[q]
                + xd0 * wr0[q] + xd1 * wr1[q]
                + e0 * we0[q] + e1 * we1[q] + e2 * we2[q];
        acc += lreluf_(v) * at[q];
      }
    }
    logit_s[h * 65 + e] = acc;
  }
  __syncthreads();

  for (int t = tid; t < HEADS * 64; t += 256) {
    int h = t >> 6, n = t & 63;
    if (n < N_NODES) {
      int s0 = start[n], dn = deg[n];
      float mx = -1e30f;
      for (int i = 0; i < dn; ++i) mx = fmaxf(mx, logit_s[h * 65 + elist[s0 + i]]);
      float den = 0.f;
      for (int i = 0; i < dn; ++i) den += expf(logit_s[h * 65 + elist[s0 + i]] - mx);
      float inv = 1.f / (den + 1e-16f);
      for (int i = 0; i < dn; ++i) {
        int e = elist[s0 + i];
        logit_s[h * 65 + e] = expf(logit_s[h * 65 + e] - mx) * inv;
      }
    }
  }
  __syncthreads();

  for (int t = tid; t < N_NODES * 64; t += 256) {
    int n = t >> 6, jb = t & 63;
    int j0 = jb * 8, h = jb >> 3;
    f32x4 wa0 = *(const f32x4*)(Wl_s + j0);
    f32x4 wa1 = *(const f32x4*)(Wl_s + j0 + 4);
    f32x4 wb0 = *(const f32x4*)(Wl_s + 512 + j0);
    f32x4 wb1 = *(const f32x4*)(Wl_s + 512 + j0 + 4);
    float acc[8] = {};
    int s0 = start[n], dn = deg[n];
    for (int i = 0; i < dn; ++i) {
      int e = elist[s0 + i]; int s = sloc[e];
      float a = logit_s[h * 65 + e];
      float ax0 = a * xs0_s[s], ax1 = a * xs1_s[s];
      #pragma unroll
      for (int q = 0; q < 4; ++q) {
        acc[q]     += ax0 * wa0[q] + ax1 * wb0[q];
        acc[4 + q] += ax0 * wa1[q] + ax1 * wb1[q];
      }
    }
    f32x4 b0 = *(const f32x4*)(bias + j0);
    f32x4 b1 = *(const f32x4*)(bias + j0 + 4);
    halfx8 vh;
    #pragma unroll
    for (int cc = 0; cc < 8; ++cc) {
      float bb = (cc < 4) ? b0[cc] : b1[cc - 4];
      vh[cc] = (half_t)eluf_(acc[cc] + bb);
    }
    *(halfx8*)(h1 + (size_t)(lb + n) * HC + j0) = vh;
  }
}

// ============================================================
// single-term fp16 MFMA GEMM (round-13 version; chunk gemm only now).
// ============================================================
template <int WM, int WN, int NP, int K, int SA, int SB, typename TC>
__global__ __launch_bounds__(256) void gemm_f16(
    const half_t* __restrict__ A, const half_t* __restrict__ B,
    TC* __restrict__ C, const float* __restrict__ bias1, const float* __restrict__ bias2,
    int M, int N) {
  constexpr int BM = 32 * WM, BN = 32 * WN;
  constexpr bool BOUNCE = (sizeof(TC) == 2) && (BM == 128) && (BN == 128);
  constexpr int STAGE_HALFS = (BM + BN) * 32 * NP;
  constexpr int CT_HALFS = BOUNCE ? 128 * 132 : 0;
  constexpr int LDS_HALFS = STAGE_HALFS > CT_HALFS ? STAGE_HALFS : CT_HALFS;
  __shared__ half_t lds[LDS_HALFS];
  half_t* A_s = lds;
  half_t* B_s = A_s + NP * BM * 32;

  const int R = M / BM, NT = N / BN;
  int b = blockIdx.x;
  int xcd = b & 7, q = b >> 3;
  int ct = q % NT, rg = q / NT;
  int r = rg * 8 + xcd;
  if (r >= R) return;

  const int tid = threadIdx.x;
  const int wave = tid >> 6, lane = tid & 63;
  const int wm = wave >> 1, wn = wave & 1;
  const int bm = r * BM, bn = ct * BN;

  const int rA = lane >> 2;
  const int swz = (rA & 3) ^ ((rA >> 2) & 3);
  const int cA = ((lane & 3) ^ swz) * 8;

  f32x4 acc[WM][WN];
  #pragma unroll
  for (int tm = 0; tm < WM; ++tm)
    #pragma unroll
    for (int tn = 0; tn < WN; ++tn) acc[tm][tn] = {0.f, 0.f, 0.f, 0.f};

  for (int k0 = 0; k0 < K; k0 += 32 * NP) {
    #pragma unroll
    for (int p = 0; p < NP; ++p) {
      int kk = k0 + p * 32;
      #pragma unroll
      for (int i = 0; i < BM / 64; ++i) {
        int row = i * 64 + wave * 16;
        gl2lds16(A + (size_t)(bm + row + rA) * SA + kk + cA,
                 A_s + p * BM * 32 + row * 32);
      }
      #pragma unroll
      for (int i = 0; i < BN / 64; ++i) {
        int row = i * 64 + wave * 16;
        gl2lds16(B + (size_t)(bn + row + rA) * SB + kk + cA,
                 B_s + p * BN * 32 + row * 32);
      }
    }
    __syncthreads();

    const int fr = lane & 15;
    const int fs = (fr & 3) ^ ((fr >> 2) & 3);
    const int fk = ((lane >> 4) ^ fs) * 8;
    #pragma unroll
    for (int p = 0; p < NP; ++p) {
      const int pA = p * BM * 32, pB = p * BN * 32;
      halfx8 af[WM], bf[WN];
      #pragma unroll
      for (int tm = 0; tm < WM; ++tm) {
        int rr = (wm * WM + tm) * 16 + fr;
        af[tm] = *(const halfx8*)(A_s + pA + rr * 32 + fk);
      }
      #pragma unroll
      for (int tn = 0; tn < WN; ++tn) {
        int rr = (wn * WN + tn) * 16 + fr;
        bf[tn] = *(const halfx8*)(B_s + pB + rr * 32 + fk);
      }
      #pragma unroll
      for (int tm = 0; tm < WM; ++tm)
        #pragma unroll
        for (int tn = 0; tn < WN; ++tn)
          acc[tm][tn] = __builtin_amdgcn_mfma_f32_16x16x32_f16(af[tm], bf[tn], acc[tm][tn], 0, 0, 0);
    }
    __syncthreads();
  }

  const int col0 = lane & 15, rq = (lane >> 4) * 4;
  if constexpr (BOUNCE) {
    half_t* Cs = lds;
    #pragma unroll
    for (int tm = 0; tm < WM; ++tm)
      #pragma unroll
      for (int tn = 0; tn < WN; ++tn) {
        int cl = (wn * WN + tn) * 16 + col0;
        #pragma unroll
        for (int rr = 0; rr < 4; ++rr) {
          int rl = (wm * WM + tm) * 16 + rq + rr;
          Cs[rl * 132 + cl] = (half_t)acc[tm][tn][rr];
        }
      }
    __syncthreads();
    #pragma unroll
    for (int pass = 0; pass < 8; ++pass) {
      int row = pass * 16 + (tid >> 4);
      int col = (tid & 15) * 8;
      halfx8 v = *(const halfx8*)(Cs + row * 132 + col);
      *(halfx8*)((half_t*)C + (size_t)(bm + row) * N + bn + col) = v;
    }
  } else {
    #pragma unroll
    for (int tm = 0; tm < WM; ++tm)
      #pragma unroll
      for (int tn = 0; tn < WN; ++tn) {
        int col = bn + (wn * WN + tn) * 16 + col0;
        float badd = 0.f;
        if (bias1) badd += bias1[col];
        if (bias2) badd += bias2[col];
        #pragma unroll
        for (int rr = 0; rr < 4; ++rr) {
          int row = bm + (wm * WM + tm) * 16 + rq + rr;
          C[(size_t)row * N + col] = (TC)(acc[tm][tn][rr] + badd);
        }
      }
  }
}

// ============================================================
// final GEMM, split-K=4 in ONE dispatch (was 192 blocks = 0.75/CU):
// grid (192, 4); part 0 covers k [0,576) and adds biases, parts 1-3 cover
// 512 each. Partials summed in lstm_all. BM=BN=64, NP=2, strides 2112.
// ============================================================
__global__ __launch_bounds__(256) void gemm_f16_splitk(
    const half_t* __restrict__ A, const half_t* __restrict__ B,
    float* __restrict__ Cp, const float* __restrict__ bias1, const float* __restrict__ bias2,
    int M, int N) {
  constexpr int SA = 2112;
  __shared__ half_t lds[(64 + 64) * 64];   // [NP=2][64][32] x2 = 16 KB
  half_t* A_s = lds;
  half_t* B_s = A_s + 2 * 64 * 32;

  const int part = blockIdx.y;
  const int koff = part ? 576 + (part - 1) * 512 : 0;
  const int kend = part ? 512 : 576;
  const half_t* Ap = A + koff;
  const half_t* Bp = B + koff;
  float* C = Cp + (size_t)part * M * N;

  const int R = M / 64, NT = N / 64;
  int b = blockIdx.x;
  int xcd = b & 7, q = b >> 3;
  int ct = q % NT, rg = q / NT;
  int r = rg * 8 + xcd;
  if (r >= R) return;

  const int tid = threadIdx.x;
  const int wave = tid >> 6, lane = tid & 63;
  const int wm = wave >> 1, wn = wave & 1;
  const int bm = r * 64, bn = ct * 64;

  const int rA = lane >> 2;
  const int swz = (rA & 3) ^ ((rA >> 2) & 3);
  const int cA = ((lane & 3) ^ swz) * 8;

  f32x4 acc[2][2];
  #pragma unroll
  for (int tm = 0; tm < 2; ++tm)
    #pragma unroll
    for (int tn = 0; tn < 2; ++tn) acc[tm][tn] = {0.f, 0.f, 0.f, 0.f};

  for (int k0 = 0; k0 < kend; k0 += 64) {
    #pragma unroll
    for (int p = 0; p < 2; ++p) {
      int kk = k0 + p * 32;
      {
        int row = wave * 16;
        gl2lds16(Ap + (size_t)(bm + row + rA) * SA + kk + cA,
                 A_s + p * 64 * 32 + row * 32);
        gl2lds16(Bp + (size_t)(bn + row + rA) * SA + kk + cA,
                 B_s + p * 64 * 32 + row * 32);
      }
    }
    __syncthreads();
    const int fr = lane & 15;
    const int fs = (fr & 3) ^ ((fr >> 2) & 3);
    const int fk = ((lane >> 4) ^ fs) * 8;
    #pragma unroll
    for (int p = 0; p < 2; ++p) {
      const int pA = p * 64 * 32, pB = p * 64 * 32;
      halfx8 af[2], bf[2];
      #pragma unroll
      for (int tm = 0; tm < 2; ++tm) {
        int rr = (wm * 2 + tm) * 16 + fr;
        af[tm] = *(const halfx8*)(A_s + pA + rr * 32 + fk);
      }
      #pragma unroll
      for (int tn = 0; tn < 2; ++tn) {
        int rr = (wn * 2 + tn) * 16 + fr;
        bf[tn] = *(const halfx8*)(B_s + pB + rr * 32 + fk);
      }
      #pragma unroll
      for (int tm = 0; tm < 2; ++tm)
        #pragma unroll
        for (int tn = 0; tn < 2; ++tn)
          acc[tm][tn] = __builtin_amdgcn_mfma_f32_16x16x32_f16(af[tm], bf[tn], acc[tm][tn], 0, 0, 0);
    }
    __syncthreads();
  }

  const int col0 = lane & 15, rq = (lane >> 4) * 4;
  #pragma unroll
  for (int tm = 0; tm < 2; ++tm)
    #pragma unroll
    for (int tn = 0; tn < 2; ++tn) {
      int col = bn + (wn * 2 + tn) * 16 + col0;
      float badd = (part == 0) ? (bias1[col] + bias2[col]) : 0.f;
      #pragma unroll
      for (int rr = 0; rr < 2 * 2; ++rr) { }
      #pragma unroll
      for (int rr = 0; rr < 4; ++rr) {
        int row = bm + (wm * 2 + tm) * 16 + rq + rr;
        C[(size_t)row * N + col] = acc[tm][tn][rr] + badd;
      }
    }
}

// ============================================================
// GAT layer 2 v4 (round-11/12 verified) -> h2 single fp16.
// ============================================================
__global__ __launch_bounds__(256) void gat2_kernel(
    const half_t* __restrict__ xlr, const int* __restrict__ src, const int* __restrict__ dst,
    const float* __restrict__ ea, const float* __restrict__ We,
    const float* __restrict__ att, const float* __restrict__ bias,
    half_t* __restrict__ h2, int g0) {
  __shared__ alignas(16) float We_s[3 * 512];
  __shared__ alignas(16) float att_s[512];
  __shared__ float b_s[HID];
  __shared__ float easX[EPG], easY[EPG], easZ[EPG];
  __shared__ float logit_s[HEADS * 65];
  __shared__ int sloc[EPG], dloc[EPG], deg[N_NODES], start[N_NODES], fill[N_NODES], elist[EPG];

  const int g = g0 + blockIdx.x, tid = threadIdx.x;
  const int nb = g * N_NODES, eb = g * EPG;
  const int lb = blockIdx.x * N_NODES;
  const int wave = tid >> 6, lane = tid & 63;

  for (int i = tid; i < 1536; i += 256) We_s[i] = We[i];
  for (int i = tid; i < 512; i += 256) att_s[i] = att[i];
  if (tid < HID) b_s[tid] = bias[tid];
  if (tid < EPG) {
    easX[tid] = ea[(eb + tid) * 3 + 0];
    easY[tid] = ea[(eb + tid) * 3 + 1];
    easZ[tid] = ea[(eb + tid) * 3 + 2];
    sloc[tid] = src[eb + tid] - nb;
    dloc[tid] = dst[eb + tid] - nb;
  }
  if (tid < N_NODES) { deg[tid] = 0; fill[tid] = 0; }
  __syncthreads();
  if (tid < EPG) atomicAdd(&deg[dloc[tid]], 1);
  __syncthreads();
  if (tid == 0) { int a = 0; for (int n = 0; n < N_NODES; ++n) { start[n] = a; a += deg[n]; } }
  __syncthreads();
  if (tid < EPG) { int d = dloc[tid]; int p = atomicAdd(&fill[d], 1); elist[start[d] + p] = tid; }
  __syncthreads();

  const int j0 = lane * 8;
  float w0[8], w1[8], w2[8], at8[8];
  #pragma unroll
  for (int q = 0; q < 8; ++q) {
    w0[q] = We_s[j0 + q];
    w1[q] = We_s[512 + j0 + q];
    w2[q] = We_s[1024 + j0 + q];
    at8[q] = att_s[j0 + q];
  }

  for (int e = wave; e < EPG; e += 4) {
    int s = sloc[e], d = dloc[e];
    halfx8 xlv = *((const halfx8*)(xlr + (size_t)(lb + s) * 1024) + lane);
    halfx8 xrv = *((const halfx8*)(xlr + (size_t)(lb + d) * 1024 + 512) + lane);
    float e0 = easX[e], e1 = easY[e], e2 = easZ[e];
    float acc = 0.f;
    #pragma unroll
    for (int q = 0; q < 8; ++q) {
      float v = (float)xlv[q] + (float)xrv[q] + e0 * w0[q] + e1 * w1[q] + e2 * w2[q];
      acc += lreluf_(v) * at8[q];
    }
    acc += __shfl_xor(acc, 1, 64);
    acc += __shfl_xor(acc, 2, 64);
    acc += __shfl_xor(acc, 4, 64);
    if ((lane & 7) == 0) logit_s[(lane >> 3) * 65 + e] = acc;
  }
  __syncthreads();

  for (int t = tid; t < HEADS * 64; t += 256) {
    int h = t >> 6, n = t & 63;
    if (n < N_NODES) {
      int s0 = start[n], dn = deg[n];
      float mx = -1e30f;
      for (int i = 0; i < dn; ++i) mx = fmaxf(mx, logit_s[h * 65 + elist[s0 + i]]);
      float den = 0.f;
      for (int i = 0; i < dn; ++i) den += expf(logit_s[h * 65 + elist[s0 + i]] - mx);
      float inv = 1.f / (den + 1e-16f);
      for (int i = 0; i < dn; ++i) {
        int e = elist[s0 + i];
        logit_s[h * 65 + e] = expf(logit_s[h * 65 + e] - mx) * inv;
      }
    }
  }
  __syncthreads();

  for (int n = wave; n < N_NODES; n += 4) {
    float acc = 0.f;
    int s0 = start[n], dn = deg[n];
    for (int i = 0; i < dn; ++i) {
      int e = elist[s0 + i], s = sloc[e];
      const half_t* row = xlr + (size_t)(lb + s) * 1024 + lane;
      #pragma unroll
      for (int h = 0; h < 8; ++h)
        acc += logit_s[h * 65 + e] * (float)row[h * 64];
    }
    float v = eluf_(acc * 0.125f + b_s[lane]);
    h2[(size_t)(nb + n) * HID + lane] = (half_t)v;
  }
}

// ============================================================
// Fused LSTM1 + x2 + LSTM2 + FC. One block per batch row, 1024 threads.
// Phase 1 = round-5 lstm1 (X = sum of 4 split-K partials); Y1 kept in LDS.
// Phase 2 = lstm2 with x2 computed on the fly: thread (j2 = tid&255,
// qt = tid>>8) holds Wih2[j2][qt*32..+31] and Whh2[j2][qt*16..+15];
// partials reduced through LDS. FC by threads 0..3.
// ============================================================
__global__ __launch_bounds__(1024, 4) void lstm_all(
    const float* __restrict__ X0, const float* __restrict__ X1,
    const float* __restrict__ X2p, const float* __restrict__ X3,
    const float* __restrict__ Whh1,
    const float* __restrict__ Wih2, const float* __restrict__ bih2,
    const float* __restrict__ bhh2, const float* __restrict__ Whh2,
    const float* __restrict__ fcW, const float* __restrict__ fcb,
    float* __restrict__ out) {
  __shared__ float hs1[LSTM1_H], cs1[LSTM1_H], p1[512], gs1[512];
  __shared__ float Y1s[SEQ][LSTM1_H];                  // 12 KB
  __shared__ float hs2[LSTM2_H], cs2[LSTM2_H], p2[4 * 256], gs2[256];
  const int tid = threadIdx.x, b = blockIdx.x;
  const int j = tid & 511, half = tid >> 9;

  // ---- phase 1: LSTM1 ----
  float4 w1[16];
  {
    const float4* wp = (const float4*)(Whh1 + (size_t)j * LSTM1_H + half * 64);
    #pragma unroll
    for (int q = 0; q < 16; ++q) w1[q] = wp[q];
  }
  if (tid < LSTM1_H) { hs1[tid] = 0.f; cs1[tid] = 0.f; }
  __syncthreads();
  for (int t = 0; t < SEQ; ++t) {
    const float* hb = hs1 + half * 64;
    float acc = 0.f;
    #pragma unroll
    for (int q = 0; q < 16; ++q) {
      acc += w1[q].x * hb[4 * q] + w1[q].y * hb[4 * q + 1]
           + w1[q].z * hb[4 * q + 2] + w1[q].w * hb[4 * q + 3];
    }
    if (half) p1[j] = acc;
    __syncthreads();
    if (!half) {
      size_t xo = ((size_t)b * SEQ + t) * 512 + j;
      gs1[j] = acc + p1[j] + X0[xo] + X1[xo] + X2p[xo] + X3[xo];
    }
    __syncthreads();
    if (tid < LSTM1_H) {
      float ig = sigmoidf_(gs1[tid]);
      float fg = sigmoidf_(gs1[LSTM1_H + tid]);
      float gg = tanhf(gs1[2 * LSTM1_H + tid]);
      float og = sigmoidf_(gs1[3 * LSTM1_H + tid]);
      float c = fg * cs1[tid] + ig * gg;
      cs1[tid] = c;
      float h = og * tanhf(c);
      hs1[tid] = h;
      Y1s[t][tid] = h;
    }
    __syncthreads();
  }

  // ---- phase 2: x2-on-the-fly + LSTM2 ----
  const int j2 = tid & 255, qt = tid >> 8;
  float4 w2x[8], w2h[4];
  {
    const float4* wxp = (const float4*)(Wih2 + (size_t)j2 * LSTM1_H + qt * 32);
    #pragma unroll
    for (int q = 0; q < 8; ++q) w2x[q] = wxp[q];
    const float4* whp = (const float4*)(Whh2 + (size_t)j2 * LSTM2_H + qt * 16);
    #pragma unroll
    for (int q = 0; q < 4; ++q) w2h[q] = whp[q];
  }
  if (tid < LSTM2_H) { hs2[tid] = 0.f; cs2[tid] = 0.f; }
  __syncthreads();
  for (int t = 0; t < SEQ; ++t) {
    const float* y = Y1s[t] + qt * 32;      // wave-uniform base
    const float* hb = hs2 + qt * 16;
    float acc = 0.f;
    #pragma unroll
    for (int q = 0; q < 8; ++q) {
      acc += w2x[q].x * y[4 * q] + w2x[q].y * y[4 * q + 1]
           + w2x[q].z * y[4 * q + 2] + w2x[q].w * y[4 * q + 3];
    }
    #pragma unroll
    for (int q = 0; q < 4; ++q) {
      acc += w2h[q].x * hb[4 * q] + w2h[q].y * hb[4 * q + 1]
           + w2h[q].z * hb[4 * q + 2] + w2h[q].w * hb[4 * q + 3];
    }
    p2[qt * 256 + j2] = acc;
    __syncthreads();
    if (qt == 0)
      gs2[j2] = p2[j2] + p2[256 + j2] + p2[512 + j2] + p2[768 + j2]
              + bih2[j2] + bhh2[j2];
    __syncthreads();
    if (tid < LSTM2_H) {
      float ig = sigmoidf_(gs2[tid]);
      float fg = sigmoidf_(gs2[LSTM2_H + tid]);
      float gg = tanhf(gs2[2 * LSTM2_H + tid]);
      float og = sigmoidf_(gs2[3 * LSTM2_H + tid]);
      float c = fg * cs2[tid] + ig * gg;
      cs2[tid] = c;
      hs2[tid] = og * tanhf(c);
    }
    __syncthreads();
  }
  if (tid < 4) {
    float acc = fcb[tid];
    #pragma unroll
    for (int k = 0; k < LSTM2_H; ++k) acc += fcW[tid * LSTM2_H + k] * hs2[k];
    out[b * 4 + tid] = acc;
  }
}

// ============================================================
extern "C" void kernel_launch(void* const* d_in, const int* in_sizes, int n_in,
                              void* d_out, int out_size, void* d_ws, size_t ws_size,
                              hipStream_t stream) {
  const float* x       = (const float*)d_in[0];
  const int*   eidx    = (const int*)d_in[1];
  const float* eattr   = (const float*)d_in[2];
  const float* g1_Wl   = (const float*)d_in[3];
  const float* g1_Wr   = (const float*)d_in[4];
  const float* g1_We   = (const float*)d_in[5];
  const float* g1_att  = (const float*)d_in[6];
  const float* g1_b    = (const float*)d_in[7];
  const float* g2_Wl   = (const float*)d_in[8];
  const float* g2_Wr   = (const float*)d_in[9];
  const float* g2_We   = (const float*)d_in[10];
  const float* g2_att  = (const float*)d_in[11];
  const float* g2_b    = (const float*)d_in[12];
  const float* l1_Wih  = (const float*)d_in[13];
  const float* l1_Whh  = (const float*)d_in[14];
  const float* l1_bih  = (const float*)d_in[15];
  const float* l1_bhh  = (const float*)d_in[16];
  const float* l2_Wih  = (const float*)d_in[17];
  const float* l2_Whh  = (const float*)d_in[18];
  const float* l2_bih  = (const float*)d_in[19];
  const float* l2_bhh  = (const float*)d_in[20];
  const float* fc_W    = (const float*)d_in[21];
  const float* fc_b    = (const float*)d_in[22];
  float* out = (float*)d_out;

  const int* src = eidx;
  const int* dst = eidx + E_EDGES;

  // ---- runtime-adaptive chunking ----
  const int cand[5] = {1, 2, 3, 4, 6};
  int nchunks = 0;
  half_t *h1 = nullptr, *xlr2c = nullptr, *h2 = nullptr, *B2 = nullptr, *W1f = nullptr;
  float *X1p = nullptr;
  int chunk_g = 0, chunk_n = 0;
  for (int ci = 0; ci < 5; ++ci) {
    int C = cand[ci];
    int CG = G_GRAPHS / C, CN = CG * N_NODES;
    char* p = (char*)d_ws;
    auto alloc = [&](size_t bytes) { char* r = p; p += (bytes + 255) & ~(size_t)255; return r; };
    half_t* t_h1    = (half_t*)alloc((size_t)CN * HC * 2);
    half_t* t_xlr2c = (half_t*)alloc((size_t)CN * 1024 * 2);
    half_t* t_h2    = (half_t*)alloc((size_t)G_GRAPHS * 2112 * 2);
    half_t* t_B2    = (half_t*)alloc((size_t)1024 * 512 * 2);
    half_t* t_W1f   = (half_t*)alloc((size_t)512 * 2112 * 2);
    float*  t_X1p   = (float*)alloc((size_t)4 * G_GRAPHS * 512 * 4);   // 12.6 MB
    if ((size_t)(p - (char*)d_ws) <= ws_size) {
      nchunks = C; chunk_g = CG; chunk_n = CN;
      h1 = t_h1; xlr2c = t_xlr2c; h2 = t_h2; B2 = t_B2; W1f = t_W1f;
      X1p = t_X1p;
      break;
    }
  }
  if (nchunks == 0) return;   // guard: zero output instead of memory fault

  for (int c = 0; c < nchunks; ++c) {
    int g0 = c * chunk_g;
    // chunk 0's gat1 also performs the fp16 weight conversion (extra blocks)
    int extra = (c == 0) ? CONV_BLOCKS : 0;
    gat1_kernel<<<chunk_g + extra, 256, 0, stream>>>(
        x, src, dst, eattr, g1_Wl, g1_Wr, g1_We, g1_att, g1_b, h1, g0, chunk_g,
        g2_Wl, g2_Wr, B2, l1_Wih, W1f);
    int R = chunk_n / 128, NT = 1024 / 128;
    int gblocks = 8 * ((R + 7) / 8) * NT;
    gemm_f16<4, 4, 2, HC, HC, HC, half_t><<<gblocks, 256, 0, stream>>>(
        h1, B2, xlr2c, (const float*)nullptr, (const float*)nullptr,
        chunk_n, 1024);
    gat2_kernel<<<chunk_g, 256, 0, stream>>>(xlr2c, src, dst, eattr, g2_We,
                                             g2_att, g2_b, h2, g0);
  }

  // X1 partials = h2 @ l1_Wih^T (+biases in part 0), split-K=4, one dispatch
  {
    dim3 grid(192, 4);   // 8*ceil(24/8)*8 = 192 blocks per part
    gemm_f16_splitk<<<grid, 256, 0, stream>>>(h2, W1f, X1p, l1_bih, l1_bhh,
                                              G_GRAPHS, 512);
  }

  // fused LSTM1 + x2 + LSTM2 + FC
  {
    size_t PS = (size_t)G_GRAPHS * 512;
    lstm_all<<<BATCH, 1024, 0, stream>>>(X1p, X1p + PS, X1p + 2 * PS, X1p + 3 * PS,
                                         l1_Whh, l2_Wih, l2_bih, l2_bhh, l2_Whh,
                                         fc_W, fc_b, out);
  }
}

// Round 15
// 344.688 us; speedup vs baseline: 1.1604x; 1.0321x over previous
//
#include <hip/hip_runtime.h>
#include <math.h>

// ---- problem constants ----
#define N_NODES 33
#define SEQ 24
#define BATCH 64
#define G_GRAPHS (BATCH * SEQ)          // 1536
#define EPG 64
#define E_EDGES (G_GRAPHS * EPG)        // 98304
#define N_TOTAL (G_GRAPHS * N_NODES)    // 50688
#define HID 64
#define HEADS 8
#define HC (HID * HEADS)                // 512
#define LSTM1_H 128
#define LSTM2_H 64
#define NEG_SLOPE 0.2f
// conv fused into gat1 chunk 0: 128 transpose tiles + 264 W1f blocks
#define CONV_BLOCKS (128 + 264)

__device__ __forceinline__ float sigmoidf_(float x) { return 1.f / (1.f + expf(-x)); }
__device__ __forceinline__ float eluf_(float x) { return x > 0.f ? x : expm1f(x); }
__device__ __forceinline__ float lreluf_(float x) { return x > 0.f ? x : NEG_SLOPE * x; }

typedef __attribute__((ext_vector_type(4))) float f32x4;
typedef _Float16 half_t;
typedef __attribute__((ext_vector_type(8))) _Float16 halfx8;

__device__ __forceinline__ void gl2lds16(const void* g, void* l) {
  __builtin_amdgcn_global_load_lds(
      (__attribute__((address_space(1))) const unsigned int*)g,
      (__attribute__((address_space(3))) unsigned int*)l, 16, 0, 0);
}

// ============================================================
// GAT layer 1, 512 threads (8 waves — round-15: latency hiding; round-14
// ran 4 waves/block). Blocks >= gat_blocks do the one-time fp16 weight
// conversion: 128 LDS-transpose tiles (coalesced both directions; the old
// path did strided 2KB reads) + 264 elementwise W1f blocks.
// ============================================================
__global__ __launch_bounds__(512) void gat1_kernel(
    const float* __restrict__ x, const int* __restrict__ src, const int* __restrict__ dst,
    const float* __restrict__ ea, const float* __restrict__ Wl, const float* __restrict__ Wr,
    const float* __restrict__ We, const float* __restrict__ att, const float* __restrict__ bias,
    half_t* __restrict__ h1, int g0, int gat_blocks,
    const float* __restrict__ g2Wl, const float* __restrict__ g2Wr,
    half_t* __restrict__ B2, const float* __restrict__ W1, half_t* __restrict__ W1f) {
  const int tid = threadIdx.x;

  __shared__ alignas(16) float Wl_s[2 * 512];
  __shared__ alignas(16) float Wr_s[2 * 512];
  __shared__ alignas(16) float We_s[3 * 512];
  __shared__ alignas(16) float att_s[512];
  __shared__ float xs0_s[N_NODES + 1], xs1_s[N_NODES + 1];
  __shared__ float easX[EPG], easY[EPG], easZ[EPG];
  __shared__ float logit_s[HEADS * 65];
  __shared__ int sloc[EPG], dloc[EPG], deg[N_NODES], start[N_NODES], fill[N_NODES], elist[EPG];
  __shared__ float tr[64 * 65];          // transpose tile (conv path)

  if ((int)blockIdx.x >= gat_blocks) {
    int cb = blockIdx.x - gat_blocks;
    if (cb < 128) {
      // transpose B2[n][k] = [Wl|Wr][k][n], 64x64 tile, coalesced both ways
      int kt = cb & 7, nt = cb >> 3;
      int k0 = kt * 64, n0 = nt * 64;
      int r = tid >> 6, c = tid & 63;
      #pragma unroll
      for (int rr = 0; rr < 8; ++rr) {
        int kl = rr * 8 + r;
        int n = n0 + c;
        float v = (n < 512) ? g2Wl[(size_t)(k0 + kl) * 512 + n]
                            : g2Wr[(size_t)(k0 + kl) * 512 + n - 512];
        tr[kl * 65 + c] = v;
      }
      __syncthreads();
      #pragma unroll
      for (int rr = 0; rr < 8; ++rr) {
        int nl = rr * 8 + r;
        B2[(size_t)(n0 + nl) * 512 + k0 + c] = (half_t)tr[c * 65 + nl];
      }
    } else {
      int base = (cb - 128) * 4096 + tid;
      #pragma unroll
      for (int i = 0; i < 8; ++i) {
        int idx = base + i * 512;
        if (idx < 512 * 2112) W1f[idx] = (half_t)W1[idx];
      }
    }
    return;
  }

  const int g = g0 + blockIdx.x;
  const int nb = g * N_NODES, eb = g * EPG;
  const int lb = blockIdx.x * N_NODES;

  for (int i = tid; i < 1024; i += 512) { Wl_s[i] = Wl[i]; Wr_s[i] = Wr[i]; }
  for (int i = tid; i < 1536; i += 512) We_s[i] = We[i];
  if (tid < 512) att_s[tid] = att[tid];
  if (tid < 2 * N_NODES) {
    float v = x[nb * 2 + tid];
    if (tid & 1) xs1_s[tid >> 1] = v; else xs0_s[tid >> 1] = v;
  }
  if (tid < EPG) {
    easX[tid] = ea[(eb + tid) * 3 + 0];
    easY[tid] = ea[(eb + tid) * 3 + 1];
    easZ[tid] = ea[(eb + tid) * 3 + 2];
    sloc[tid] = src[eb + tid] - nb;
    dloc[tid] = dst[eb + tid] - nb;
  }
  if (tid < N_NODES) { deg[tid] = 0; fill[tid] = 0; }
  __syncthreads();
  if (tid < EPG) atomicAdd(&deg[dloc[tid]], 1);
  __syncthreads();
  if (tid == 0) { int a = 0; for (int n = 0; n < N_NODES; ++n) { start[n] = a; a += deg[n]; } }
  __syncthreads();
  if (tid < EPG) { int d = dloc[tid]; int p = atomicAdd(&fill[d], 1); elist[start[d] + p] = tid; }

  // logits: one pass, h = tid>>6 (wave-uniform), e = lane
  {
    int h = tid >> 6, e = tid & 63;
    int s = sloc[e], d = dloc[e];
    float xs0 = xs0_s[s], xs1 = xs1_s[s], xd0 = xs0_s[d], xd1 = xs1_s[d];
    float e0 = easX[e], e1 = easY[e], e2 = easZ[e];
    float acc = 0.f;
    int base = h * 64;
    #pragma unroll
    for (int c4 = 0; c4 < 16; ++c4) {
      int j = base + c4 * 4;
      f32x4 wl0 = *(const f32x4*)(Wl_s + j);
      f32x4 wl1 = *(const f32x4*)(Wl_s + 512 + j);
      f32x4 wr0 = *(const f32x4*)(Wr_s + j);
      f32x4 wr1 = *(const f32x4*)(Wr_s + 512 + j);
      f32x4 we0 = *(const f32x4*)(We_s + j);
      f32x4 we1 = *(const f32x4*)(We_s + 512 + j);
      f32x4 we2 = *(const f32x4*)(We_s + 1024 + j);
      f32x4 at  = *(const f32x4*)(att_s + j);
      #pragma unroll
      for (int q = 0; q < 4; ++q) {
        float v = xs0 * wl0[q] + xs1 * wl1[q]
                + xd0 * wr0[q] + xd1 * wr1[q]
                + e0 * we0[q] + e1 * we1[q] + e2 * we2[q];
        acc += lreluf_(v) * at[q];
      }
    }
    logit_s[h * 65 + e] = acc;
  }
  __syncthreads();

  // segment softmax: one pass, h = tid>>6, n = lane (skip n>=33)
  {
    int h = tid >> 6, n = tid & 63;
    if (n < N_NODES) {
      int s0 = start[n], dn = deg[n];
      float mx = -1e30f;
      for (int i = 0; i < dn; ++i) mx = fmaxf(mx, logit_s[h * 65 + elist[s0 + i]]);
      float den = 0.f;
      for (int i = 0; i < dn; ++i) den += expf(logit_s[h * 65 + elist[s0 + i]] - mx);
      float inv = 1.f / (den + 1e-16f);
      for (int i = 0; i < dn; ++i) {
        int e = elist[s0 + i];
        logit_s[h * 65 + e] = expf(logit_s[h * 65 + e] - mx) * inv;
      }
    }
  }
  __syncthreads();

  // aggregation: task = (n, 8-channel block); n = t>>6 wave-uniform, jb = lane
  for (int t = tid; t < N_NODES * 64; t += 512) {
    int n = t >> 6, jb = t & 63;
    int j0 = jb * 8, h = jb >> 3;
    f32x4 wa0 = *(const f32x4*)(Wl_s + j0);
    f32x4 wa1 = *(const f32x4*)(Wl_s + j0 + 4);
    f32x4 wb0 = *(const f32x4*)(Wl_s + 512 + j0);
    f32x4 wb1 = *(const f32x4*)(Wl_s + 512 + j0 + 4);
    float acc[8] = {};
    int s0 = start[n], dn = deg[n];
    for (int i = 0; i < dn; ++i) {
      int e = elist[s0 + i]; int s = sloc[e];
      float a = logit_s[h * 65 + e];
      float ax0 = a * xs0_s[s], ax1 = a * xs1_s[s];
      #pragma unroll
      for (int q = 0; q < 4; ++q) {
        acc[q]     += ax0 * wa0[q] + ax1 * wb0[q];
        acc[4 + q] += ax0 * wa1[q] + ax1 * wb1[q];
      }
    }
    f32x4 b0 = *(const f32x4*)(bias + j0);
    f32x4 b1 = *(const f32x4*)(bias + j0 + 4);
    halfx8 vh;
    #pragma unroll
    for (int cc = 0; cc < 8; ++cc) {
      float bb = (cc < 4) ? b0[cc] : b1[cc - 4];
      vh[cc] = (half_t)eluf_(acc[cc] + bb);
    }
    *(halfx8*)(h1 + (size_t)(lb + n) * HC + j0) = vh;
  }
}

// ============================================================
// single-term fp16 MFMA GEMM (round-13 version — plateau-verified;
// chunk gemm only). ROUND-6 LESSON: never stream an MFMA operand
// global->VGPR.
// ============================================================
template <int WM, int WN, int NP, int K, int SA, int SB, typename TC>
__global__ __launch_bounds__(256) void gemm_f16(
    const half_t* __restrict__ A, const half_t* __restrict__ B,
    TC* __restrict__ C, const float* __restrict__ bias1, const float* __restrict__ bias2,
    int M, int N) {
  constexpr int BM = 32 * WM, BN = 32 * WN;
  constexpr bool BOUNCE = (sizeof(TC) == 2) && (BM == 128) && (BN == 128);
  constexpr int STAGE_HALFS = (BM + BN) * 32 * NP;
  constexpr int CT_HALFS = BOUNCE ? 128 * 132 : 0;
  constexpr int LDS_HALFS = STAGE_HALFS > CT_HALFS ? STAGE_HALFS : CT_HALFS;
  __shared__ half_t lds[LDS_HALFS];
  half_t* A_s = lds;
  half_t* B_s = A_s + NP * BM * 32;

  const int R = M / BM, NT = N / BN;
  int b = blockIdx.x;
  int xcd = b & 7, q = b >> 3;
  int ct = q % NT, rg = q / NT;
  int r = rg * 8 + xcd;
  if (r >= R) return;

  const int tid = threadIdx.x;
  const int wave = tid >> 6, lane = tid & 63;
  const int wm = wave >> 1, wn = wave & 1;
  const int bm = r * BM, bn = ct * BN;

  const int rA = lane >> 2;
  const int swz = (rA & 3) ^ ((rA >> 2) & 3);
  const int cA = ((lane & 3) ^ swz) * 8;

  f32x4 acc[WM][WN];
  #pragma unroll
  for (int tm = 0; tm < WM; ++tm)
    #pragma unroll
    for (int tn = 0; tn < WN; ++tn) acc[tm][tn] = {0.f, 0.f, 0.f, 0.f};

  for (int k0 = 0; k0 < K; k0 += 32 * NP) {
    #pragma unroll
    for (int p = 0; p < NP; ++p) {
      int kk = k0 + p * 32;
      #pragma unroll
      for (int i = 0; i < BM / 64; ++i) {
        int row = i * 64 + wave * 16;
        gl2lds16(A + (size_t)(bm + row + rA) * SA + kk + cA,
                 A_s + p * BM * 32 + row * 32);
      }
      #pragma unroll
      for (int i = 0; i < BN / 64; ++i) {
        int row = i * 64 + wave * 16;
        gl2lds16(B + (size_t)(bn + row + rA) * SB + kk + cA,
                 B_s + p * BN * 32 + row * 32);
      }
    }
    __syncthreads();

    const int fr = lane & 15;
    const int fs = (fr & 3) ^ ((fr >> 2) & 3);
    const int fk = ((lane >> 4) ^ fs) * 8;
    #pragma unroll
    for (int p = 0; p < NP; ++p) {
      const int pA = p * BM * 32, pB = p * BN * 32;
      halfx8 af[WM], bf[WN];
      #pragma unroll
      for (int tm = 0; tm < WM; ++tm) {
        int rr = (wm * WM + tm) * 16 + fr;
        af[tm] = *(const halfx8*)(A_s + pA + rr * 32 + fk);
      }
      #pragma unroll
      for (int tn = 0; tn < WN; ++tn) {
        int rr = (wn * WN + tn) * 16 + fr;
        bf[tn] = *(const halfx8*)(B_s + pB + rr * 32 + fk);
      }
      #pragma unroll
      for (int tm = 0; tm < WM; ++tm)
        #pragma unroll
        for (int tn = 0; tn < WN; ++tn)
          acc[tm][tn] = __builtin_amdgcn_mfma_f32_16x16x32_f16(af[tm], bf[tn], acc[tm][tn], 0, 0, 0);
    }
    __syncthreads();
  }

  const int col0 = lane & 15, rq = (lane >> 4) * 4;
  if constexpr (BOUNCE) {
    half_t* Cs = lds;
    #pragma unroll
    for (int tm = 0; tm < WM; ++tm)
      #pragma unroll
      for (int tn = 0; tn < WN; ++tn) {
        int cl = (wn * WN + tn) * 16 + col0;
        #pragma unroll
        for (int rr = 0; rr < 4; ++rr) {
          int rl = (wm * WM + tm) * 16 + rq + rr;
          Cs[rl * 132 + cl] = (half_t)acc[tm][tn][rr];
        }
      }
    __syncthreads();
    #pragma unroll
    for (int pass = 0; pass < 8; ++pass) {
      int row = pass * 16 + (tid >> 4);
      int col = (tid & 15) * 8;
      halfx8 v = *(const halfx8*)(Cs + row * 132 + col);
      *(halfx8*)((half_t*)C + (size_t)(bm + row) * N + bn + col) = v;
    }
  } else {
    #pragma unroll
    for (int tm = 0; tm < WM; ++tm)
      #pragma unroll
      for (int tn = 0; tn < WN; ++tn) {
        int col = bn + (wn * WN + tn) * 16 + col0;
        float badd = 0.f;
        if (bias1) badd += bias1[col];
        if (bias2) badd += bias2[col];
        #pragma unroll
        for (int rr = 0; rr < 4; ++rr) {
          int row = bm + (wm * WM + tm) * 16 + rq + rr;
          C[(size_t)row * N + col] = (TC)(acc[tm][tn][rr] + badd);
        }
      }
  }
}

// ============================================================
// final GEMM, split-K=4 in one dispatch (round-14 verified)
// ============================================================
__global__ __launch_bounds__(256) void gemm_f16_splitk(
    const half_t* __restrict__ A, const half_t* __restrict__ B,
    float* __restrict__ Cp, const float* __restrict__ bias1, const float* __restrict__ bias2,
    int M, int N) {
  constexpr int SA = 2112;
  __shared__ half_t lds[(64 + 64) * 64];
  half_t* A_s = lds;
  half_t* B_s = A_s + 2 * 64 * 32;

  const int part = blockIdx.y;
  const int koff = part ? 576 + (part - 1) * 512 : 0;
  const int kend = part ? 512 : 576;
  const half_t* Ap = A + koff;
  const half_t* Bp = B + koff;
  float* C = Cp + (size_t)part * M * N;

  const int R = M / 64, NT = N / 64;
  int b = blockIdx.x;
  int xcd = b & 7, q = b >> 3;
  int ct = q % NT, rg = q / NT;
  int r = rg * 8 + xcd;
  if (r >= R) return;

  const int tid = threadIdx.x;
  const int wave = tid >> 6, lane = tid & 63;
  const int wm = wave >> 1, wn = wave & 1;
  const int bm = r * 64, bn = ct * 64;

  const int rA = lane >> 2;
  const int swz = (rA & 3) ^ ((rA >> 2) & 3);
  const int cA = ((lane & 3) ^ swz) * 8;

  f32x4 acc[2][2];
  #pragma unroll
  for (int tm = 0; tm < 2; ++tm)
    #pragma unroll
    for (int tn = 0; tn < 2; ++tn) acc[tm][tn] = {0.f, 0.f, 0.f, 0.f};

  for (int k0 = 0; k0 < kend; k0 += 64) {
    #pragma unroll
    for (int p = 0; p < 2; ++p) {
      int kk = k0 + p * 32;
      int row = wave * 16;
      gl2lds16(Ap + (size_t)(bm + row + rA) * SA + kk + cA,
               A_s + p * 64 * 32 + row * 32);
      gl2lds16(Bp + (size_t)(bn + row + rA) * SA + kk + cA,
               B_s + p * 64 * 32 + row * 32);
    }
    __syncthreads();
    const int fr = lane & 15;
    const int fs = (fr & 3) ^ ((fr >> 2) & 3);
    const int fk = ((lane >> 4) ^ fs) * 8;
    #pragma unroll
    for (int p = 0; p < 2; ++p) {
      const int pA = p * 64 * 32, pB = p * 64 * 32;
      halfx8 af[2], bf[2];
      #pragma unroll
      for (int tm = 0; tm < 2; ++tm) {
        int rr = (wm * 2 + tm) * 16 + fr;
        af[tm] = *(const halfx8*)(A_s + pA + rr * 32 + fk);
      }
      #pragma unroll
      for (int tn = 0; tn < 2; ++tn) {
        int rr = (wn * 2 + tn) * 16 + fr;
        bf[tn] = *(const halfx8*)(B_s + pB + rr * 32 + fk);
      }
      #pragma unroll
      for (int tm = 0; tm < 2; ++tm)
        #pragma unroll
        for (int tn = 0; tn < 2; ++tn)
          acc[tm][tn] = __builtin_amdgcn_mfma_f32_16x16x32_f16(af[tm], bf[tn], acc[tm][tn], 0, 0, 0);
    }
    __syncthreads();
  }

  const int col0 = lane & 15, rq = (lane >> 4) * 4;
  #pragma unroll
  for (int tm = 0; tm < 2; ++tm)
    #pragma unroll
    for (int tn = 0; tn < 2; ++tn) {
      int col = bn + (wn * 2 + tn) * 16 + col0;
      float badd = (part == 0) ? (bias1[col] + bias2[col]) : 0.f;
      #pragma unroll
      for (int rr = 0; rr < 4; ++rr) {
        int row = bm + (wm * 2 + tm) * 16 + rq + rr;
        C[(size_t)row * N + col] = acc[tm][tn][rr] + badd;
      }
    }
}

// ============================================================
// GAT layer 2, 512 threads (8 waves — round-15 latency hiding).
// ============================================================
__global__ __launch_bounds__(512) void gat2_kernel(
    const half_t* __restrict__ xlr, const int* __restrict__ src, const int* __restrict__ dst,
    const float* __restrict__ ea, const float* __restrict__ We,
    const float* __restrict__ att, const float* __restrict__ bias,
    half_t* __restrict__ h2, int g0) {
  __shared__ alignas(16) float We_s[3 * 512];
  __shared__ alignas(16) float att_s[512];
  __shared__ float b_s[HID];
  __shared__ float easX[EPG], easY[EPG], easZ[EPG];
  __shared__ float logit_s[HEADS * 65];
  __shared__ int sloc[EPG], dloc[EPG], deg[N_NODES], start[N_NODES], fill[N_NODES], elist[EPG];

  const int g = g0 + blockIdx.x, tid = threadIdx.x;
  const int nb = g * N_NODES, eb = g * EPG;
  const int lb = blockIdx.x * N_NODES;
  const int wave = tid >> 6, lane = tid & 63;

  for (int i = tid; i < 1536; i += 512) We_s[i] = We[i];
  if (tid < 512) att_s[tid] = att[tid];
  if (tid < HID) b_s[tid] = bias[tid];
  if (tid < EPG) {
    easX[tid] = ea[(eb + tid) * 3 + 0];
    easY[tid] = ea[(eb + tid) * 3 + 1];
    easZ[tid] = ea[(eb + tid) * 3 + 2];
    sloc[tid] = src[eb + tid] - nb;
    dloc[tid] = dst[eb + tid] - nb;
  }
  if (tid < N_NODES) { deg[tid] = 0; fill[tid] = 0; }
  __syncthreads();
  if (tid < EPG) atomicAdd(&deg[dloc[tid]], 1);
  __syncthreads();
  if (tid == 0) { int a = 0; for (int n = 0; n < N_NODES; ++n) { start[n] = a; a += deg[n]; } }
  __syncthreads();
  if (tid < EPG) { int d = dloc[tid]; int p = atomicAdd(&fill[d], 1); elist[start[d] + p] = tid; }
  __syncthreads();

  const int j0 = lane * 8;
  float w0[8], w1[8], w2[8], at8[8];
  #pragma unroll
  for (int q = 0; q < 8; ++q) {
    w0[q] = We_s[j0 + q];
    w1[q] = We_s[512 + j0 + q];
    w2[q] = We_s[1024 + j0 + q];
    at8[q] = att_s[j0 + q];
  }

  // logits: one wave per edge (8 iterations at 8 waves)
  for (int e = wave; e < EPG; e += 8) {
    int s = sloc[e], d = dloc[e];
    halfx8 xlv = *((const halfx8*)(xlr + (size_t)(lb + s) * 1024) + lane);
    halfx8 xrv = *((const halfx8*)(xlr + (size_t)(lb + d) * 1024 + 512) + lane);
    float e0 = easX[e], e1 = easY[e], e2 = easZ[e];
    float acc = 0.f;
    #pragma unroll
    for (int q = 0; q < 8; ++q) {
      float v = (float)xlv[q] + (float)xrv[q] + e0 * w0[q] + e1 * w1[q] + e2 * w2[q];
      acc += lreluf_(v) * at8[q];
    }
    acc += __shfl_xor(acc, 1, 64);
    acc += __shfl_xor(acc, 2, 64);
    acc += __shfl_xor(acc, 4, 64);
    if ((lane & 7) == 0) logit_s[(lane >> 3) * 65 + e] = acc;
  }
  __syncthreads();

  // softmax: one pass, h = tid>>6, n = lane (skip n>=33)
  {
    int h = tid >> 6, n = tid & 63;
    if (n < N_NODES) {
      int s0 = start[n], dn = deg[n];
      float mx = -1e30f;
      for (int i = 0; i < dn; ++i) mx = fmaxf(mx, logit_s[h * 65 + elist[s0 + i]]);
      float den = 0.f;
      for (int i = 0; i < dn; ++i) den += expf(logit_s[h * 65 + elist[s0 + i]] - mx);
      float inv = 1.f / (den + 1e-16f);
      for (int i = 0; i < dn; ++i) {
        int e = elist[s0 + i];
        logit_s[h * 65 + e] = expf(logit_s[h * 65 + e] - mx) * inv;
      }
    }
  }
  __syncthreads();

  // aggregation: wave-task n (5 iterations at 8 waves), lane = HID channel
  for (int n = wave; n < N_NODES; n += 8) {
    float acc = 0.f;
    int s0 = start[n], dn = deg[n];
    for (int i = 0; i < dn; ++i) {
      int e = elist[s0 + i], s = sloc[e];
      const half_t* row = xlr + (size_t)(lb + s) * 1024 + lane;
      #pragma unroll
      for (int h = 0; h < 8; ++h)
        acc += logit_s[h * 65 + e] * (float)row[h * 64];
    }
    float v = eluf_(acc * 0.125f + b_s[lane]);
    h2[(size_t)(nb + n) * HID + lane] = (half_t)v;
  }
}

// ============================================================
// Fused LSTM1 + x2 + LSTM2 + FC (round-14 verified)
// ============================================================
__global__ __launch_bounds__(1024, 4) void lstm_all(
    const float* __restrict__ X0, const float* __restrict__ X1,
    const float* __restrict__ X2p, const float* __restrict__ X3,
    const float* __restrict__ Whh1,
    const float* __restrict__ Wih2, const float* __restrict__ bih2,
    const float* __restrict__ bhh2, const float* __restrict__ Whh2,
    const float* __restrict__ fcW, const float* __restrict__ fcb,
    float* __restrict__ out) {
  __shared__ float hs1[LSTM1_H], cs1[LSTM1_H], p1[512], gs1[512];
  __shared__ float Y1s[SEQ][LSTM1_H];
  __shared__ float hs2[LSTM2_H], cs2[LSTM2_H], p2[4 * 256], gs2[256];
  const int tid = threadIdx.x, b = blockIdx.x;
  const int j = tid & 511, half = tid >> 9;

  float4 w1[16];
  {
    const float4* wp = (const float4*)(Whh1 + (size_t)j * LSTM1_H + half * 64);
    #pragma unroll
    for (int q = 0; q < 16; ++q) w1[q] = wp[q];
  }
  if (tid < LSTM1_H) { hs1[tid] = 0.f; cs1[tid] = 0.f; }
  __syncthreads();
  for (int t = 0; t < SEQ; ++t) {
    const float* hb = hs1 + half * 64;
    float acc = 0.f;
    #pragma unroll
    for (int q = 0; q < 16; ++q) {
      acc += w1[q].x * hb[4 * q] + w1[q].y * hb[4 * q + 1]
           + w1[q].z * hb[4 * q + 2] + w1[q].w * hb[4 * q + 3];
    }
    if (half) p1[j] = acc;
    __syncthreads();
    if (!half) {
      size_t xo = ((size_t)b * SEQ + t) * 512 + j;
      gs1[j] = acc + p1[j] + X0[xo] + X1[xo] + X2p[xo] + X3[xo];
    }
    __syncthreads();
    if (tid < LSTM1_H) {
      float ig = sigmoidf_(gs1[tid]);
      float fg = sigmoidf_(gs1[LSTM1_H + tid]);
      float gg = tanhf(gs1[2 * LSTM1_H + tid]);
      float og = sigmoidf_(gs1[3 * LSTM1_H + tid]);
      float c = fg * cs1[tid] + ig * gg;
      cs1[tid] = c;
      float h = og * tanhf(c);
      hs1[tid] = h;
      Y1s[t][tid] = h;
    }
    __syncthreads();
  }

  const int j2 = tid & 255, qt = tid >> 8;
  float4 w2x[8], w2h[4];
  {
    const float4* wxp = (const float4*)(Wih2 + (size_t)j2 * LSTM1_H + qt * 32);
    #pragma unroll
    for (int q = 0; q < 8; ++q) w2x[q] = wxp[q];
    const float4* whp = (const float4*)(Whh2 + (size_t)j2 * LSTM2_H + qt * 16);
    #pragma unroll
    for (int q = 0; q < 4; ++q) w2h[q] = whp[q];
  }
  if (tid < LSTM2_H) { hs2[tid] = 0.f; cs2[tid] = 0.f; }
  __syncthreads();
  for (int t = 0; t < SEQ; ++t) {
    const float* y = Y1s[t] + qt * 32;
    const float* hb = hs2 + qt * 16;
    float acc = 0.f;
    #pragma unroll
    for (int q = 0; q < 8; ++q) {
      acc += w2x[q].x * y[4 * q] + w2x[q].y * y[4 * q + 1]
           + w2x[q].z * y[4 * q + 2] + w2x[q].w * y[4 * q + 3];
    }
    #pragma unroll
    for (int q = 0; q < 4; ++q) {
      acc += w2h[q].x * hb[4 * q] + w2h[q].y * hb[4 * q + 1]
           + w2h[q].z * hb[4 * q + 2] + w2h[q].w * hb[4 * q + 3];
    }
    p2[qt * 256 + j2] = acc;
    __syncthreads();
    if (qt == 0)
      gs2[j2] = p2[j2] + p2[256 + j2] + p2[512 + j2] + p2[768 + j2]
              + bih2[j2] + bhh2[j2];
    __syncthreads();
    if (tid < LSTM2_H) {
      float ig = sigmoidf_(gs2[tid]);
      float fg = sigmoidf_(gs2[LSTM2_H + tid]);
      float gg = tanhf(gs2[2 * LSTM2_H + tid]);
      float og = sigmoidf_(gs2[3 * LSTM2_H + tid]);
      float c = fg * cs2[tid] + ig * gg;
      cs2[tid] = c;
      hs2[tid] = og * tanhf(c);
    }
    __syncthreads();
  }
  if (tid < 4) {
    float acc = fcb[tid];
    #pragma unroll
    for (int k = 0; k < LSTM2_H; ++k) acc += fcW[tid * LSTM2_H + k] * hs2[k];
    out[b * 4 + tid] = acc;
  }
}

// ============================================================
extern "C" void kernel_launch(void* const* d_in, const int* in_sizes, int n_in,
                              void* d_out, int out_size, void* d_ws, size_t ws_size,
                              hipStream_t stream) {
  const float* x       = (const float*)d_in[0];
  const int*   eidx    = (const int*)d_in[1];
  const float* eattr   = (const float*)d_in[2];
  const float* g1_Wl   = (const float*)d_in[3];
  const float* g1_Wr   = (const float*)d_in[4];
  const float* g1_We   = (const float*)d_in[5];
  const float* g1_att  = (const float*)d_in[6];
  const float* g1_b    = (const float*)d_in[7];
  const float* g2_Wl   = (const float*)d_in[8];
  const float* g2_Wr   = (const float*)d_in[9];
  const float* g2_We   = (const float*)d_in[10];
  const float* g2_att  = (const float*)d_in[11];
  const float* g2_b    = (const float*)d_in[12];
  const float* l1_Wih  = (const float*)d_in[13];
  const float* l1_Whh  = (const float*)d_in[14];
  const float* l1_bih  = (const float*)d_in[15];
  const float* l1_bhh  = (const float*)d_in[16];
  const float* l2_Wih  = (const float*)d_in[17];
  const float* l2_Whh  = (const float*)d_in[18];
  const float* l2_bih  = (const float*)d_in[19];
  const float* l2_bhh  = (const float*)d_in[20];
  const float* fc_W    = (const float*)d_in[21];
  const float* fc_b    = (const float*)d_in[22];
  float* out = (float*)d_out;

  const int* src = eidx;
  const int* dst = eidx + E_EDGES;

  // ---- runtime-adaptive chunking ----
  const int cand[5] = {1, 2, 3, 4, 6};
  int nchunks = 0;
  half_t *h1 = nullptr, *xlr2c = nullptr, *h2 = nullptr, *B2 = nullptr, *W1f = nullptr;
  float *X1p = nullptr;
  int chunk_g = 0, chunk_n = 0;
  for (int ci = 0; ci < 5; ++ci) {
    int C = cand[ci];
    int CG = G_GRAPHS / C, CN = CG * N_NODES;
    char* p = (char*)d_ws;
    auto alloc = [&](size_t bytes) { char* r = p; p += (bytes + 255) & ~(size_t)255; return r; };
    half_t* t_h1    = (half_t*)alloc((size_t)CN * HC * 2);
    half_t* t_xlr2c = (half_t*)alloc((size_t)CN * 1024 * 2);
    half_t* t_h2    = (half_t*)alloc((size_t)G_GRAPHS * 2112 * 2);
    half_t* t_B2    = (half_t*)alloc((size_t)1024 * 512 * 2);
    half_t* t_W1f   = (half_t*)alloc((size_t)512 * 2112 * 2);
    float*  t_X1p   = (float*)alloc((size_t)4 * G_GRAPHS * 512 * 4);
    if ((size_t)(p - (char*)d_ws) <= ws_size) {
      nchunks = C; chunk_g = CG; chunk_n = CN;
      h1 = t_h1; xlr2c = t_xlr2c; h2 = t_h2; B2 = t_B2; W1f = t_W1f;
      X1p = t_X1p;
      break;
    }
  }
  if (nchunks == 0) return;   // guard: zero output instead of memory fault

  for (int c = 0; c < nchunks; ++c) {
    int g0 = c * chunk_g;
    int extra = (c == 0) ? CONV_BLOCKS : 0;
    gat1_kernel<<<chunk_g + extra, 512, 0, stream>>>(
        x, src, dst, eattr, g1_Wl, g1_Wr, g1_We, g1_att, g1_b, h1, g0, chunk_g,
        g2_Wl, g2_Wr, B2, l1_Wih, W1f);
    int R = chunk_n / 128, NT = 1024 / 128;
    int gblocks = 8 * ((R + 7) / 8) * NT;
    gemm_f16<4, 4, 2, HC, HC, HC, half_t><<<gblocks, 256, 0, stream>>>(
        h1, B2, xlr2c, (const float*)nullptr, (const float*)nullptr,
        chunk_n, 1024);
    gat2_kernel<<<chunk_g, 512, 0, stream>>>(xlr2c, src, dst, eattr, g2_We,
                                             g2_att, g2_b, h2, g0);
  }

  // X1 partials = h2 @ l1_Wih^T (+biases in part 0), split-K=4, one dispatch
  {
    dim3 grid(192, 4);
    gemm_f16_splitk<<<grid, 256, 0, stream>>>(h2, W1f, X1p, l1_bih, l1_bhh,
                                              G_GRAPHS, 512);
  }

  // fused LSTM1 + x2 + LSTM2 + FC
  {
    size_t PS = (size_t)G_GRAPHS * 512;
    lstm_all<<<BATCH, 1024, 0, stream>>>(X1p, X1p + PS, X1p + 2 * PS, X1p + 3 * PS,
                                         l1_Whh, l2_Wih, l2_bih, l2_bhh, l2_Whh,
                                         fc_W, fc_b, out);
  }
}